// Round 8
// baseline (222.324 us; speedup 1.0000x reference)
//
#include <hip/hip_runtime.h>
#include <math.h>

// Round 8 = Round 7 + the missing barrier. R7's NaN: Ps (K-loop strips) and
// Comb (combine buffer) are a union, but there was no __syncthreads between
// the end of the K-loop and the comb publish -> wave A's f32 O-partials
// overwrote wave B's live P strip (float halves read as bf16 => NaN).
// Fix: one __syncthreads() after the K-loop, before publishing.

typedef __bf16 bf16x8 __attribute__((ext_vector_type(8)));
typedef float  f32x4  __attribute__((ext_vector_type(4)));
typedef unsigned u32x2 __attribute__((ext_vector_type(2)));
typedef unsigned u32x4 __attribute__((ext_vector_type(4)));
typedef unsigned short ushort_t;

__device__ __forceinline__ unsigned short f2bf(float f) {
    unsigned u = __float_as_uint(f);
    u += 0x7fffu + ((u >> 16) & 1u);          // round-to-nearest-even
    return (unsigned short)(u >> 16);
}
__device__ __forceinline__ unsigned pk16(unsigned short lo, unsigned short hi) {
    return (unsigned)lo | ((unsigned)hi << 16);
}

#define GLL16(g, l)                                                                        \
    __builtin_amdgcn_global_load_lds((const __attribute__((address_space(1))) void*)(g),   \
                                     (__attribute__((address_space(3))) void*)(l), 16, 0, 0)

// ---------------------------------------------------------------------------
// cast fp32 -> bf16: y=0 -> x, y=1..4 -> Wq,Wk,Wv,Wo
// ---------------------------------------------------------------------------
__global__ __launch_bounds__(256)
void cast_all(const float* __restrict__ x,
              const float* __restrict__ w0, const float* __restrict__ w1,
              const float* __restrict__ w2, const float* __restrict__ w3,
              ushort_t* __restrict__ xb, ushort_t* __restrict__ wb0,
              ushort_t* __restrict__ wb1, ushort_t* __restrict__ wb2,
              ushort_t* __restrict__ wb3)
{
    const int y = blockIdx.y;
    const float* s; ushort_t* d; int n;
    switch (y) {
        case 0:  s = x;  d = xb;  n = 8192 * 768; break;
        case 1:  s = w0; d = wb0; n = 768 * 768;  break;
        case 2:  s = w1; d = wb1; n = 768 * 768;  break;
        case 3:  s = w2; d = wb2; n = 768 * 768;  break;
        default: s = w3; d = wb3; n = 768 * 768;  break;
    }
    const int i = (blockIdx.x * 256 + threadIdx.x) * 8;
    if (i >= n) return;
    const float4 f0 = *(const float4*)(s + i);
    const float4 f1 = *(const float4*)(s + i + 4);
    ushort4 p0, p1;
    p0.x = f2bf(f0.x); p0.y = f2bf(f0.y); p0.z = f2bf(f0.z); p0.w = f2bf(f0.w);
    p1.x = f2bf(f1.x); p1.y = f2bf(f1.y); p1.z = f2bf(f1.z); p1.w = f2bf(f1.w);
    *(ushort4*)(d + i)     = p0;
    *(ushort4*)(d + i + 4) = p1;
}

// ---------------------------------------------------------------------------
// GEMM core: C128x128 = A . W^T, 16x16x32 bf16 MFMA.
// XOR-swizzled LDS: staged slot s of row r holds global chunk s ^ ((r>>1)&3);
// frag read uses slot g ^ ((c>>1)&3) -> returns chunk g, 2-way banks (free).
// ---------------------------------------------------------------------------
__device__ __forceinline__ void gemm_core_mfma(
    const ushort_t* __restrict__ A, const ushort_t* __restrict__ W,
    int m0, int n0, ushort_t* smem, f32x4 acc[4][4])
{
    ushort_t* As = smem;            // 4096 shorts
    ushort_t* Ws = smem + 4096;     // 4096 shorts
    const int tid = threadIdx.x;
    const int L   = tid & 63;
    const int wv  = tid >> 6;
    const int wr  = wv >> 1, wc = wv & 1;
    const int c   = L & 15,  g  = L >> 4;

    const int c0 = tid, c1 = tid + 256;
    const int qs = ((tid & 3) ^ ((tid >> 3) & 3)) * 8;   // swizzled k-chunk
    const ushort_t* a0 = A + (size_t)(m0 + (c0 >> 2)) * 768 + qs;
    const ushort_t* a1 = A + (size_t)(m0 + (c1 >> 2)) * 768 + qs;
    const ushort_t* w0 = W + (size_t)(n0 + (c0 >> 2)) * 768 + qs;
    const ushort_t* w1 = W + (size_t)(n0 + (c1 >> 2)) * 768 + qs;
    const int sg = (g ^ ((c >> 1) & 3)) * 8;             // swizzled read col

#pragma unroll
    for (int i = 0; i < 4; ++i)
#pragma unroll
        for (int j = 0; j < 4; ++j) acc[i][j] = (f32x4){0.f, 0.f, 0.f, 0.f};

    for (int k0 = 0; k0 < 768; k0 += 32) {
        __syncthreads();
        GLL16(a0 + k0, &As[(size_t)c0 * 8]);
        GLL16(a1 + k0, &As[(size_t)c1 * 8]);
        GLL16(w0 + k0, &Ws[(size_t)c0 * 8]);
        GLL16(w1 + k0, &Ws[(size_t)c1 * 8]);
        __syncthreads();
        bf16x8 af[4], bfr[4];
#pragma unroll
        for (int i = 0; i < 4; ++i)
            af[i] = *(const bf16x8*)&As[(wr * 64 + i * 16 + c) * 32 + sg];
#pragma unroll
        for (int j = 0; j < 4; ++j)
            bfr[j] = *(const bf16x8*)&Ws[(wc * 64 + j * 16 + c) * 32 + sg];
#pragma unroll
        for (int i = 0; i < 4; ++i)
#pragma unroll
            for (int j = 0; j < 4; ++j)
                acc[i][j] = __builtin_amdgcn_mfma_f32_16x16x32_bf16(
                    af[i], bfr[j], acc[i][j], 0, 0, 0);
    }
}

// ---------------------------------------------------------------------------
// QKV: z=0 Q -> [bh][n][64]; z=1 K frag-linear; z=2 V frag-linear.
// Epilogues transpose through LDS scratch -> 16B coalesced stores only.
// ---------------------------------------------------------------------------
__global__ __launch_bounds__(256, 3)
void gemm_qkv(const ushort_t* __restrict__ xb,
              const ushort_t* __restrict__ wqb, const ushort_t* __restrict__ wkb,
              const ushort_t* __restrict__ wvb,
              const float* __restrict__ bq, const float* __restrict__ bk,
              const float* __restrict__ bv,
              ushort_t* __restrict__ Qh, ushort_t* __restrict__ Kl,
              ushort_t* __restrict__ Vl)
{
    __shared__ ushort_t smem[8192];
    const int z = blockIdx.z;
    const ushort_t* W   = (z == 0) ? wqb : (z == 1) ? wkb : wvb;
    const float*    bia = (z == 0) ? bq  : (z == 1) ? bk  : bv;
    const int m0 = blockIdx.y * 128, n0 = blockIdx.x * 128;
    f32x4 acc[4][4];
    gemm_core_mfma(xb, W, m0, n0, smem, acc);

    const int tid = threadIdx.x, L = tid & 63, wv2 = tid >> 6;
    const int wr = wv2 >> 1, wc = wv2 & 1, c = L & 15, g = L >> 4;
    ushort_t* scr = smem + wv2 * 1280;          // 2560 B per wave
    const int h = (n0 + wc * 64) >> 6;          // one head per wave-col-block
    float bsv[4];
#pragma unroll
    for (int j = 0; j < 4; ++j) bsv[j] = bia[n0 + wc * 64 + j * 16 + c];

    __syncthreads();    // staging LDS now reusable as scratch
#pragma unroll
    for (int i = 0; i < 4; ++i) {
        const int rowg = m0 + wr * 64 + i * 16;   // 16-row block, one batch
        const int b  = rowg >> 10;
        const int nb = rowg & 1023;
        const int bh = b * 12 + h;
        if (z < 2) {
            // scratch [row16][col64] stride 72
#pragma unroll
            for (int j = 0; j < 4; ++j)
#pragma unroll
                for (int r = 0; r < 4; ++r)
                    scr[(g * 4 + r) * 72 + j * 16 + c] = f2bf(acc[i][j][r] + bsv[j]);
            if (z == 0) {
                const int row = L >> 2, qp = L & 3;
                const u32x4 v0 = *(const u32x4*)&scr[row * 72 + qp * 16];
                const u32x4 v1 = *(const u32x4*)&scr[row * 72 + qp * 16 + 8];
                ushort_t* dst = Qh + ((size_t)bh * 1024 + nb + row) * 64 + qp * 16;
                *(u32x4*)dst       = v0;
                *(u32x4*)(dst + 8) = v1;
            } else {
                const int n16 = L >> 2, q1 = L & 3;
                const u32x4 va  = *(const u32x4*)&scr[n16 * 72 + q1 * 8];
                const u32x4 vb2 = *(const u32x4*)&scr[n16 * 72 + q1 * 8 + 32];
                ushort_t* base = Kl + (size_t)bh * 65536 + (size_t)(nb >> 4) * 1024;
                *(u32x4*)&base[q1 * 128 + n16 * 8]       = va;
                *(u32x4*)&base[512 + q1 * 128 + n16 * 8] = vb2;
            }
        } else {
            // scratch [hd64][n16] stride 20, r-pairs packed b32
#pragma unroll
            for (int j = 0; j < 4; ++j) {
                const unsigned w01 = pk16(f2bf(acc[i][j][0] + bsv[j]),
                                          f2bf(acc[i][j][1] + bsv[j]));
                const unsigned w23 = pk16(f2bf(acc[i][j][2] + bsv[j]),
                                          f2bf(acc[i][j][3] + bsv[j]));
                const int a = (j * 16 + c) * 20 + g * 4;
                *(unsigned*)&scr[a]     = w01;
                *(unsigned*)&scr[a + 2] = w23;
            }
            const u32x2 r0 = *(const u32x2*)&scr[L * 20];
            const u32x2 r1 = *(const u32x2*)&scr[L * 20 + 4];
            const u32x2 r2 = *(const u32x2*)&scr[L * 20 + 8];
            const u32x2 r3 = *(const u32x2*)&scr[L * 20 + 12];
            const int ht = L >> 4, cV = L & 15;
            const int T = nb >> 6, u = (nb >> 5) & 1, gVa = (nb >> 3) & 3;
            ushort_t* vb = Vl + (((size_t)(bh * 4 + ht) * 16 + T) * 2 + u) * 512 + cV * 8;
            *(u32x4*)&vb[gVa * 128]       = (u32x4){r0.x, r0.y, r1.x, r1.y};
            *(u32x4*)&vb[(gVa + 1) * 128] = (u32x4){r2.x, r2.y, r3.x, r3.y};
        }
    }
}

__global__ __launch_bounds__(256, 3)
void gemm_outp(const ushort_t* __restrict__ attnb, const ushort_t* __restrict__ wob,
               const float* __restrict__ bo, float* __restrict__ out)
{
    __shared__ ushort_t smem[8192];
    const int m0 = blockIdx.y * 128, n0 = blockIdx.x * 128;
    f32x4 acc[4][4];
    gemm_core_mfma(attnb, wob, m0, n0, smem, acc);
    const int tid = threadIdx.x, L = tid & 63, wv2 = tid >> 6;
    const int wr = wv2 >> 1, wc = wv2 & 1, c = L & 15, g = L >> 4;
#pragma unroll
    for (int i = 0; i < 4; ++i) {
        const int row = m0 + wr * 64 + i * 16 + g * 4;
#pragma unroll
        for (int j = 0; j < 4; ++j) {
            const int col = n0 + wc * 64 + j * 16 + c;
            const float bsvo = bo[col];
#pragma unroll
            for (int r = 0; r < 4; ++r)
                out[(size_t)(row + r) * 768 + col] = acc[i][j][r] + bsvo;
        }
    }
}

// ---------------------------------------------------------------------------
// Flash v6b: S^T = K.Q^T, fixed-max softmax (m=0), 2-wave T-split.
// In-place K prefetch, early V issue, bare v_exp_f32. LDS = union{P-strips |
// combine}. Barrier AFTER the K-loop protects the union; barrier between
// publish and read orders the cross-wave combine.
// ---------------------------------------------------------------------------
union FlashSmem {
    ushort_t ps[2][2][16 * 68];    // [wave][qgroup] strips, 8704 B
    f32x4 comb[2][64 * 5];         // [qgroup][lane*5 + (o0..o3,l)], 10240 B
};

__global__ __launch_bounds__(128, 3)
void flash_bf16(const ushort_t* __restrict__ Q, const ushort_t* __restrict__ Kl,
                const ushort_t* __restrict__ Vl, ushort_t* __restrict__ attnb)
{
    __shared__ FlashSmem sm;
    const int tid = threadIdx.x;
    const int wv = tid >> 6, L = tid & 63, c = L & 15, g = L >> 4;
    const int bh = blockIdx.y, q0 = blockIdx.x * 32;
    const float SC2 = 0.05205954985329743f;    // 768^-0.5 * log2(e)

    const ushort_t* Qp = Q + ((size_t)bh * 1024 + q0 + c) * 64 + g * 8;
    bf16x8 qf[2][2];
    qf[0][0] = *(const bf16x8*)Qp;
    qf[0][1] = *(const bf16x8*)(Qp + 32);
    qf[1][0] = *(const bf16x8*)(Qp + 1024);
    qf[1][1] = *(const bf16x8*)(Qp + 1056);

    const ushort_t* Kb = Kl + (size_t)bh * 65536 + (size_t)L * 8;
    const ushort_t* Vb = Vl + (size_t)bh * 65536 + (size_t)L * 8;

    f32x4 o[2][4];
#pragma unroll
    for (int w = 0; w < 2; ++w)
#pragma unroll
        for (int ht = 0; ht < 4; ++ht) o[w][ht] = (f32x4){0.f, 0.f, 0.f, 0.f};
    float ls[2] = {0.f, 0.f};

    const int Tbeg = wv * 8, Tend = Tbeg + 8;

    // preload first K tile
    bf16x8 kf0[4], kf1[4];
#pragma unroll
    for (int ct = 0; ct < 4; ++ct) {
        const ushort_t* kp = Kb + (size_t)((Tbeg * 4 + ct) * 2) * 512;
        kf0[ct] = *(const bf16x8*)kp;
        kf1[ct] = *(const bf16x8*)(kp + 512);
    }

    for (int T = Tbeg; T < Tend; ++T) {
        // V frags: issue early (independent of the S chain)
        bf16x8 vf0[4], vf1[4];
#pragma unroll
        for (int ht = 0; ht < 4; ++ht) {
            const ushort_t* vp = Vb + (size_t)((ht * 16 + T) * 2) * 512;
            vf0[ht] = *(const bf16x8*)vp;
            vf1[ht] = *(const bf16x8*)(vp + 512);
        }
        // S^T for both q-groups (consumes kf)
        f32x4 s[2][4];
#pragma unroll
        for (int w = 0; w < 2; ++w)
#pragma unroll
            for (int ct = 0; ct < 4; ++ct) {
                f32x4 zz = (f32x4){0.f, 0.f, 0.f, 0.f};
                zz = __builtin_amdgcn_mfma_f32_16x16x32_bf16(kf0[ct], qf[w][0], zz, 0, 0, 0);
                zz = __builtin_amdgcn_mfma_f32_16x16x32_bf16(kf1[ct], qf[w][1], zz, 0, 0, 0);
                s[w][ct] = zz;
            }
        // in-place K prefetch for next iteration (no extra registers)
        const int Tn = (T + 1 < Tend) ? T + 1 : T;
#pragma unroll
        for (int ct = 0; ct < 4; ++ct) {
            const ushort_t* kp = Kb + (size_t)((Tn * 4 + ct) * 2) * 512;
            kf0[ct] = *(const bf16x8*)kp;
            kf1[ct] = *(const bf16x8*)(kp + 512);
        }
        // fixed-max softmax: bare v_exp_f32, direct p-sum, perm pack
#pragma unroll
        for (int w = 0; w < 2; ++w) {
#pragma unroll
            for (int ct = 0; ct < 4; ++ct) {
                float p[4];
#pragma unroll
                for (int r = 0; r < 4; ++r)
                    p[r] = __builtin_amdgcn_exp2f(s[w][ct][r] * SC2);
                ls[w] += (p[0] + p[1]) + (p[2] + p[3]);
                const unsigned w01 = __builtin_amdgcn_perm(
                    __float_as_uint(p[1]), __float_as_uint(p[0]), 0x07060302u);
                const unsigned w23 = __builtin_amdgcn_perm(
                    __float_as_uint(p[3]), __float_as_uint(p[2]), 0x07060302u);
                *(u32x2*)&sm.ps[wv][w][c * 68 + ct * 16 + g * 4] = (u32x2){w01, w23};
            }
        }
        // P^T as B-frags; O^T += V^T . P^T
        const int pb = c * 68 + g * 8;
#pragma unroll
        for (int w = 0; w < 2; ++w) {
            const bf16x8 pf0 = __builtin_bit_cast(bf16x8, *(const u32x4*)&sm.ps[wv][w][pb]);
            const bf16x8 pf1 = __builtin_bit_cast(bf16x8, *(const u32x4*)&sm.ps[wv][w][pb + 32]);
#pragma unroll
            for (int ht = 0; ht < 4; ++ht) {
                o[w][ht] = __builtin_amdgcn_mfma_f32_16x16x32_bf16(vf0[ht], pf0, o[w][ht], 0, 0, 0);
                o[w][ht] = __builtin_amdgcn_mfma_f32_16x16x32_bf16(vf1[ht], pf1, o[w][ht], 0, 0, 0);
            }
        }
    }

    // ---- the fix: both waves must be done with ps before comb overwrites it
    __syncthreads();

    // cross-wave combine: wave wv publishes its partial for qgroup (wv^1),
    // then combines + writes qgroup wv.
    const int other = wv ^ 1;
#pragma unroll
    for (int ht = 0; ht < 4; ++ht) sm.comb[other][L * 5 + ht] = o[other][ht];
    sm.comb[other][L * 5 + 4] = (f32x4){ls[other], 0.f, 0.f, 0.f};
    __syncthreads();

    f32x4 oc[4];
#pragma unroll
    for (int ht = 0; ht < 4; ++ht) oc[ht] = o[wv][ht] + sm.comb[wv][L * 5 + ht];
    float lc = ls[wv] + sm.comb[wv][L * 5 + 4].x;
    lc += __shfl_xor(lc, 16);
    lc += __shfl_xor(lc, 32);
    const float inv = 1.f / lc;

    // strip transpose within this wave's comb region (it already read it)
    ushort_t* strip = (ushort_t*)&sm.comb[wv][0];
#pragma unroll
    for (int ht = 0; ht < 4; ++ht) {
        const unsigned w0 = pk16(f2bf(oc[ht][0] * inv), f2bf(oc[ht][1] * inv));
        const unsigned w1 = pk16(f2bf(oc[ht][2] * inv), f2bf(oc[ht][3] * inv));
        *(u32x2*)&strip[c * 68 + ht * 16 + g * 4] = (u32x2){w0, w1};
    }
    const int b = bh / 12, h = bh % 12;
#pragma unroll
    for (int e = 0; e < 2; ++e) {
        const int row = e * 8 + (L >> 3);
        const int ch  = L & 7;
        const int si  = row * 68 + ch * 8;
        const u32x2 t0 = *(const u32x2*)&strip[si];
        const u32x2 t1 = *(const u32x2*)&strip[si + 4];
        *(u32x4*)&attnb[((size_t)(b * 1024 + q0 + wv * 16 + row)) * 768 + h * 64 + ch * 8]
            = (u32x4){t0.x, t0.y, t1.x, t1.y};
    }
}

extern "C" void kernel_launch(void* const* d_in, const int* in_sizes, int n_in,
                              void* d_out, int out_size, void* d_ws, size_t ws_size,
                              hipStream_t stream)
{
    const float* x  = (const float*)d_in[0];
    const float* Wq = (const float*)d_in[1];
    const float* bq = (const float*)d_in[2];
    const float* Wk = (const float*)d_in[3];
    const float* bk = (const float*)d_in[4];
    const float* Wv = (const float*)d_in[5];
    const float* bv = (const float*)d_in[6];
    const float* Wo = (const float*)d_in[7];
    const float* bo = (const float*)d_in[8];
    float* out = (float*)d_out;

    char* ws = (char*)d_ws;
    ushort_t* xb    = (ushort_t*)(ws);
    ushort_t* wqb   = (ushort_t*)(ws + 12582912);
    ushort_t* wkb   = (ushort_t*)(ws + 12582912 + 1179648);
    ushort_t* wvb   = (ushort_t*)(ws + 12582912 + 2359296);
    ushort_t* wob   = (ushort_t*)(ws + 12582912 + 3538944);
    ushort_t* Qh    = (ushort_t*)(ws + 17301504);
    ushort_t* Kl    = (ushort_t*)(ws + 29884416);
    ushort_t* Vl    = (ushort_t*)(ws + 42467328);
    ushort_t* attnb = (ushort_t*)(ws + 55050240);

    cast_all<<<dim3(3072, 5), 256, 0, stream>>>(x, Wq, Wk, Wv, Wo,
                                                xb, wqb, wkb, wvb, wob);
    gemm_qkv<<<dim3(6, 64, 3), 256, 0, stream>>>(xb, wqb, wkb, wvb,
                                                 bq, bk, bv, Qh, Kl, Vl);
    flash_bf16<<<dim3(32, 96), 128, 0, stream>>>(Qh, Kl, Vl, attnb);
    gemm_outp<<<dim3(6, 64), 256, 0, stream>>>(attnb, wob, bo, out);
}

// Round 9
// 198.709 us; speedup vs baseline: 1.1188x; 1.1188x over previous
//
#include <hip/hip_runtime.h>
#include <math.h>

// Round 9: flash reverted to the R5 1-wave structure (empirically best:
// <57us vs 64-68us for all T-split variants), plus (a) bare v_exp_f32 via
// __builtin_amdgcn_exp2f (libm exp2f was ~20 ops/value -> dominant VALU
// load), (b) direct p-sum for l, (c) grid transposed to (bh, qtile) so all
// 32 q-tiles of one bh land on one XCD (linear-id stride 96 = 0 mod 8) ->
// K/V L2-resident per XCD, FETCH 109->~45MB. GEMMs unchanged from R8
// (XOR-swizzled staging, bounds(256,3), LDS-transposed epilogues).

typedef __bf16 bf16x8 __attribute__((ext_vector_type(8)));
typedef float  f32x4  __attribute__((ext_vector_type(4)));
typedef unsigned u32x2 __attribute__((ext_vector_type(2)));
typedef unsigned u32x4 __attribute__((ext_vector_type(4)));
typedef unsigned short ushort_t;

__device__ __forceinline__ unsigned short f2bf(float f) {
    unsigned u = __float_as_uint(f);
    u += 0x7fffu + ((u >> 16) & 1u);          // round-to-nearest-even
    return (unsigned short)(u >> 16);
}
__device__ __forceinline__ unsigned pk16(unsigned short lo, unsigned short hi) {
    return (unsigned)lo | ((unsigned)hi << 16);
}

#define GLL16(g, l)                                                                        \
    __builtin_amdgcn_global_load_lds((const __attribute__((address_space(1))) void*)(g),   \
                                     (__attribute__((address_space(3))) void*)(l), 16, 0, 0)

// ---------------------------------------------------------------------------
// cast fp32 -> bf16: y=0 -> x, y=1..4 -> Wq,Wk,Wv,Wo
// ---------------------------------------------------------------------------
__global__ __launch_bounds__(256)
void cast_all(const float* __restrict__ x,
              const float* __restrict__ w0, const float* __restrict__ w1,
              const float* __restrict__ w2, const float* __restrict__ w3,
              ushort_t* __restrict__ xb, ushort_t* __restrict__ wb0,
              ushort_t* __restrict__ wb1, ushort_t* __restrict__ wb2,
              ushort_t* __restrict__ wb3)
{
    const int y = blockIdx.y;
    const float* s; ushort_t* d; int n;
    switch (y) {
        case 0:  s = x;  d = xb;  n = 8192 * 768; break;
        case 1:  s = w0; d = wb0; n = 768 * 768;  break;
        case 2:  s = w1; d = wb1; n = 768 * 768;  break;
        case 3:  s = w2; d = wb2; n = 768 * 768;  break;
        default: s = w3; d = wb3; n = 768 * 768;  break;
    }
    const int i = (blockIdx.x * 256 + threadIdx.x) * 8;
    if (i >= n) return;
    const float4 f0 = *(const float4*)(s + i);
    const float4 f1 = *(const float4*)(s + i + 4);
    ushort4 p0, p1;
    p0.x = f2bf(f0.x); p0.y = f2bf(f0.y); p0.z = f2bf(f0.z); p0.w = f2bf(f0.w);
    p1.x = f2bf(f1.x); p1.y = f2bf(f1.y); p1.z = f2bf(f1.z); p1.w = f2bf(f1.w);
    *(ushort4*)(d + i)     = p0;
    *(ushort4*)(d + i + 4) = p1;
}

// ---------------------------------------------------------------------------
// GEMM core: C128x128 = A . W^T, 16x16x32 bf16 MFMA.
// XOR-swizzled LDS staging -> ds_read_b128 at 2-way banks (free).
// ---------------------------------------------------------------------------
__device__ __forceinline__ void gemm_core_mfma(
    const ushort_t* __restrict__ A, const ushort_t* __restrict__ W,
    int m0, int n0, ushort_t* smem, f32x4 acc[4][4])
{
    ushort_t* As = smem;            // 4096 shorts
    ushort_t* Ws = smem + 4096;     // 4096 shorts
    const int tid = threadIdx.x;
    const int L   = tid & 63;
    const int wv  = tid >> 6;
    const int wr  = wv >> 1, wc = wv & 1;
    const int c   = L & 15,  g  = L >> 4;

    const int c0 = tid, c1 = tid + 256;
    const int qs = ((tid & 3) ^ ((tid >> 3) & 3)) * 8;   // swizzled k-chunk
    const ushort_t* a0 = A + (size_t)(m0 + (c0 >> 2)) * 768 + qs;
    const ushort_t* a1 = A + (size_t)(m0 + (c1 >> 2)) * 768 + qs;
    const ushort_t* w0 = W + (size_t)(n0 + (c0 >> 2)) * 768 + qs;
    const ushort_t* w1 = W + (size_t)(n0 + (c1 >> 2)) * 768 + qs;
    const int sg = (g ^ ((c >> 1) & 3)) * 8;             // swizzled read col

#pragma unroll
    for (int i = 0; i < 4; ++i)
#pragma unroll
        for (int j = 0; j < 4; ++j) acc[i][j] = (f32x4){0.f, 0.f, 0.f, 0.f};

    for (int k0 = 0; k0 < 768; k0 += 32) {
        __syncthreads();
        GLL16(a0 + k0, &As[(size_t)c0 * 8]);
        GLL16(a1 + k0, &As[(size_t)c1 * 8]);
        GLL16(w0 + k0, &Ws[(size_t)c0 * 8]);
        GLL16(w1 + k0, &Ws[(size_t)c1 * 8]);
        __syncthreads();
        bf16x8 af[4], bfr[4];
#pragma unroll
        for (int i = 0; i < 4; ++i)
            af[i] = *(const bf16x8*)&As[(wr * 64 + i * 16 + c) * 32 + sg];
#pragma unroll
        for (int j = 0; j < 4; ++j)
            bfr[j] = *(const bf16x8*)&Ws[(wc * 64 + j * 16 + c) * 32 + sg];
#pragma unroll
        for (int i = 0; i < 4; ++i)
#pragma unroll
            for (int j = 0; j < 4; ++j)
                acc[i][j] = __builtin_amdgcn_mfma_f32_16x16x32_bf16(
                    af[i], bfr[j], acc[i][j], 0, 0, 0);
    }
}

// ---------------------------------------------------------------------------
// QKV: z=0 Q -> [bh][n][64]; z=1 K frag-linear; z=2 V frag-linear.
// Epilogues transpose through LDS scratch -> 16B coalesced stores only.
// ---------------------------------------------------------------------------
__global__ __launch_bounds__(256, 3)
void gemm_qkv(const ushort_t* __restrict__ xb,
              const ushort_t* __restrict__ wqb, const ushort_t* __restrict__ wkb,
              const ushort_t* __restrict__ wvb,
              const float* __restrict__ bq, const float* __restrict__ bk,
              const float* __restrict__ bv,
              ushort_t* __restrict__ Qh, ushort_t* __restrict__ Kl,
              ushort_t* __restrict__ Vl)
{
    __shared__ ushort_t smem[8192];
    const int z = blockIdx.z;
    const ushort_t* W   = (z == 0) ? wqb : (z == 1) ? wkb : wvb;
    const float*    bia = (z == 0) ? bq  : (z == 1) ? bk  : bv;
    const int m0 = blockIdx.y * 128, n0 = blockIdx.x * 128;
    f32x4 acc[4][4];
    gemm_core_mfma(xb, W, m0, n0, smem, acc);

    const int tid = threadIdx.x, L = tid & 63, wv2 = tid >> 6;
    const int wr = wv2 >> 1, wc = wv2 & 1, c = L & 15, g = L >> 4;
    ushort_t* scr = smem + wv2 * 1280;          // 2560 B per wave
    const int h = (n0 + wc * 64) >> 6;          // one head per wave-col-block
    float bsv[4];
#pragma unroll
    for (int j = 0; j < 4; ++j) bsv[j] = bia[n0 + wc * 64 + j * 16 + c];

    __syncthreads();    // staging LDS now reusable as scratch
#pragma unroll
    for (int i = 0; i < 4; ++i) {
        const int rowg = m0 + wr * 64 + i * 16;   // 16-row block, one batch
        const int b  = rowg >> 10;
        const int nb = rowg & 1023;
        const int bh = b * 12 + h;
        if (z < 2) {
            // scratch [row16][col64] stride 72
#pragma unroll
            for (int j = 0; j < 4; ++j)
#pragma unroll
                for (int r = 0; r < 4; ++r)
                    scr[(g * 4 + r) * 72 + j * 16 + c] = f2bf(acc[i][j][r] + bsv[j]);
            if (z == 0) {
                const int row = L >> 2, qp = L & 3;
                const u32x4 v0 = *(const u32x4*)&scr[row * 72 + qp * 16];
                const u32x4 v1 = *(const u32x4*)&scr[row * 72 + qp * 16 + 8];
                ushort_t* dst = Qh + ((size_t)bh * 1024 + nb + row) * 64 + qp * 16;
                *(u32x4*)dst       = v0;
                *(u32x4*)(dst + 8) = v1;
            } else {
                const int n16 = L >> 2, q1 = L & 3;
                const u32x4 va  = *(const u32x4*)&scr[n16 * 72 + q1 * 8];
                const u32x4 vb2 = *(const u32x4*)&scr[n16 * 72 + q1 * 8 + 32];
                ushort_t* base = Kl + (size_t)bh * 65536 + (size_t)(nb >> 4) * 1024;
                *(u32x4*)&base[q1 * 128 + n16 * 8]       = va;
                *(u32x4*)&base[512 + q1 * 128 + n16 * 8] = vb2;
            }
        } else {
            // scratch [hd64][n16] stride 20, r-pairs packed b32
#pragma unroll
            for (int j = 0; j < 4; ++j) {
                const unsigned w01 = pk16(f2bf(acc[i][j][0] + bsv[j]),
                                          f2bf(acc[i][j][1] + bsv[j]));
                const unsigned w23 = pk16(f2bf(acc[i][j][2] + bsv[j]),
                                          f2bf(acc[i][j][3] + bsv[j]));
                const int a = (j * 16 + c) * 20 + g * 4;
                *(unsigned*)&scr[a]     = w01;
                *(unsigned*)&scr[a + 2] = w23;
            }
            const u32x2 r0 = *(const u32x2*)&scr[L * 20];
            const u32x2 r1 = *(const u32x2*)&scr[L * 20 + 4];
            const u32x2 r2 = *(const u32x2*)&scr[L * 20 + 8];
            const u32x2 r3 = *(const u32x2*)&scr[L * 20 + 12];
            const int ht = L >> 4, cV = L & 15;
            const int T = nb >> 6, u = (nb >> 5) & 1, gVa = (nb >> 3) & 3;
            ushort_t* vb = Vl + (((size_t)(bh * 4 + ht) * 16 + T) * 2 + u) * 512 + cV * 8;
            *(u32x4*)&vb[gVa * 128]       = (u32x4){r0.x, r0.y, r1.x, r1.y};
            *(u32x4*)&vb[(gVa + 1) * 128] = (u32x4){r2.x, r2.y, r3.x, r3.y};
        }
    }
}

__global__ __launch_bounds__(256, 3)
void gemm_outp(const ushort_t* __restrict__ attnb, const ushort_t* __restrict__ wob,
               const float* __restrict__ bo, float* __restrict__ out)
{
    __shared__ ushort_t smem[8192];
    const int m0 = blockIdx.y * 128, n0 = blockIdx.x * 128;
    f32x4 acc[4][4];
    gemm_core_mfma(attnb, wob, m0, n0, smem, acc);
    const int tid = threadIdx.x, L = tid & 63, wv2 = tid >> 6;
    const int wr = wv2 >> 1, wc = wv2 & 1, c = L & 15, g = L >> 4;
#pragma unroll
    for (int i = 0; i < 4; ++i) {
        const int row = m0 + wr * 64 + i * 16 + g * 4;
#pragma unroll
        for (int j = 0; j < 4; ++j) {
            const int col = n0 + wc * 64 + j * 16 + c;
            const float bsvo = bo[col];
#pragma unroll
            for (int r = 0; r < 4; ++r)
                out[(size_t)(row + r) * 768 + col] = acc[i][j][r] + bsvo;
        }
    }
}

// ---------------------------------------------------------------------------
// Flash (R5 structure): S^T = K.Q^T, fixed-max softmax (m=0), 1 wave/block,
// 32 q-rows. Grid (96 bh, 32 qtile): q-tiles of one bh share an XCD
// (linear-id stride 96 = 0 mod 8) -> K/V L2-resident. All K/V loads are
// coalesced 1KB dwordx4 (frag-linear layouts). Bare v_exp_f32 softmax.
// ---------------------------------------------------------------------------
__global__ __launch_bounds__(64, 3)
void flash_bf16(const ushort_t* __restrict__ Q, const ushort_t* __restrict__ Kl,
                const ushort_t* __restrict__ Vl, ushort_t* __restrict__ attnb)
{
    __shared__ ushort_t Ps[2][16 * 68];        // per-q-group strip
    const int L = threadIdx.x;                 // 0..63
    const int c = L & 15, g = L >> 4;
    const int bh = blockIdx.x, q0 = blockIdx.y * 32;
    const float SC2 = 0.05205954985329743f;    // 768^-0.5 * log2(e)

    // Q as B-frag for two 16-row groups
    const ushort_t* Qp = Q + ((size_t)bh * 1024 + q0 + c) * 64 + g * 8;
    bf16x8 qf[2][2];
    qf[0][0] = *(const bf16x8*)Qp;
    qf[0][1] = *(const bf16x8*)(Qp + 32);
    qf[1][0] = *(const bf16x8*)(Qp + 16 * 64);
    qf[1][1] = *(const bf16x8*)(Qp + 16 * 64 + 32);

    // frag-linear bases: lane L owns offset L*8 shorts within each 512-block
    const ushort_t* Kb = Kl + (size_t)bh * 65536 + (size_t)L * 8;
    const ushort_t* Vb = Vl + (size_t)bh * 65536 + (size_t)L * 8;

    f32x4 o[2][4];
#pragma unroll
    for (int w = 0; w < 2; ++w)
#pragma unroll
        for (int ht = 0; ht < 4; ++ht) o[w][ht] = (f32x4){0.f, 0.f, 0.f, 0.f};
    float ls[2] = {0.f, 0.f};

    // preload K tile 0
    bf16x8 kf0[4], kf1[4];
#pragma unroll
    for (int ct = 0; ct < 4; ++ct) {
        kf0[ct] = *(const bf16x8*)(Kb + (size_t)(ct * 2 + 0) * 512);
        kf1[ct] = *(const bf16x8*)(Kb + (size_t)(ct * 2 + 1) * 512);
    }

    for (int T = 0; T < 16; ++T) {
        // V frags (coalesced; used after softmax -> latency covered)
        bf16x8 vf0[4], vf1[4];
#pragma unroll
        for (int ht = 0; ht < 4; ++ht) {
            const ushort_t* vp = Vb + (size_t)((ht * 16 + T) * 2) * 512;
            vf0[ht] = *(const bf16x8*)vp;
            vf1[ht] = *(const bf16x8*)(vp + 512);
        }
        // S^T for both q-groups
        f32x4 s[2][4];
#pragma unroll
        for (int w = 0; w < 2; ++w)
#pragma unroll
            for (int ct = 0; ct < 4; ++ct) {
                f32x4 zz = (f32x4){0.f, 0.f, 0.f, 0.f};
                zz = __builtin_amdgcn_mfma_f32_16x16x32_bf16(kf0[ct], qf[w][0], zz, 0, 0, 0);
                zz = __builtin_amdgcn_mfma_f32_16x16x32_bf16(kf1[ct], qf[w][1], zz, 0, 0, 0);
                s[w][ct] = zz;
            }
        // prefetch next K tile (in place, after S consumed kf)
        const int Tn = (T < 15) ? T + 1 : 15;
#pragma unroll
        for (int ct = 0; ct < 4; ++ct) {
            const ushort_t* kp = Kb + (size_t)((Tn * 4 + ct) * 2) * 512;
            kf0[ct] = *(const bf16x8*)kp;
            kf1[ct] = *(const bf16x8*)(kp + 512);
        }
        // fixed-max softmax: bare v_exp_f32, direct p-sum, perm-truncate pack
#pragma unroll
        for (int w = 0; w < 2; ++w) {
#pragma unroll
            for (int ct = 0; ct < 4; ++ct) {
                float p[4];
#pragma unroll
                for (int r = 0; r < 4; ++r)
                    p[r] = __builtin_amdgcn_exp2f(s[w][ct][r] * SC2);
                ls[w] += (p[0] + p[1]) + (p[2] + p[3]);
                const unsigned w01 = __builtin_amdgcn_perm(
                    __float_as_uint(p[1]), __float_as_uint(p[0]), 0x07060302u);
                const unsigned w23 = __builtin_amdgcn_perm(
                    __float_as_uint(p[3]), __float_as_uint(p[2]), 0x07060302u);
                *(u32x2*)&Ps[w][c * 68 + ct * 16 + g * 4] = (u32x2){w01, w23};
            }
        }
        // read back as B-frags and accumulate O^T += V^T . P^T
#pragma unroll
        for (int w = 0; w < 2; ++w) {
            const int pb = c * 68 + g * 8;
            const u32x4 pa  = *(const u32x4*)&Ps[w][pb];
            const u32x4 pbv = *(const u32x4*)&Ps[w][pb + 32];
            const bf16x8 pf0 = __builtin_bit_cast(bf16x8, pa);
            const bf16x8 pf1 = __builtin_bit_cast(bf16x8, pbv);
#pragma unroll
            for (int ht = 0; ht < 4; ++ht) {
                o[w][ht] = __builtin_amdgcn_mfma_f32_16x16x32_bf16(vf0[ht], pf0, o[w][ht], 0, 0, 0);
                o[w][ht] = __builtin_amdgcn_mfma_f32_16x16x32_bf16(vf1[ht], pf1, o[w][ht], 0, 0, 0);
            }
        }
    }

    const int b = bh / 12, h = bh % 12;
#pragma unroll
    for (int w = 0; w < 2; ++w) {
        float l = ls[w];
        l += __shfl_xor(l, 16);
        l += __shfl_xor(l, 32);
        const float inv = 1.f / l;
        // O^T[hd][q=c] -> strip[q][hd] -> coalesced 16B stores
#pragma unroll
        for (int ht = 0; ht < 4; ++ht) {
            const unsigned w0 = pk16(f2bf(o[w][ht][0] * inv), f2bf(o[w][ht][1] * inv));
            const unsigned w1 = pk16(f2bf(o[w][ht][2] * inv), f2bf(o[w][ht][3] * inv));
            *(u32x2*)&Ps[w][c * 68 + ht * 16 + g * 4] = (u32x2){w0, w1};
        }
#pragma unroll
        for (int e = 0; e < 2; ++e) {
            const int row = e * 8 + (L >> 3);
            const int ch  = L & 7;
            const int si  = row * 68 + ch * 8;
            const u32x2 t0 = *(const u32x2*)&Ps[w][si];
            const u32x2 t1 = *(const u32x2*)&Ps[w][si + 4];
            *(u32x4*)&attnb[((size_t)(b * 1024 + q0 + w * 16 + row)) * 768 + h * 64 + ch * 8]
                = (u32x4){t0.x, t0.y, t1.x, t1.y};
        }
    }
}

extern "C" void kernel_launch(void* const* d_in, const int* in_sizes, int n_in,
                              void* d_out, int out_size, void* d_ws, size_t ws_size,
                              hipStream_t stream)
{
    const float* x  = (const float*)d_in[0];
    const float* Wq = (const float*)d_in[1];
    const float* bq = (const float*)d_in[2];
    const float* Wk = (const float*)d_in[3];
    const float* bk = (const float*)d_in[4];
    const float* Wv = (const float*)d_in[5];
    const float* bv = (const float*)d_in[6];
    const float* Wo = (const float*)d_in[7];
    const float* bo = (const float*)d_in[8];
    float* out = (float*)d_out;

    char* ws = (char*)d_ws;
    ushort_t* xb    = (ushort_t*)(ws);
    ushort_t* wqb   = (ushort_t*)(ws + 12582912);
    ushort_t* wkb   = (ushort_t*)(ws + 12582912 + 1179648);
    ushort_t* wvb   = (ushort_t*)(ws + 12582912 + 2359296);
    ushort_t* wob   = (ushort_t*)(ws + 12582912 + 3538944);
    ushort_t* Qh    = (ushort_t*)(ws + 17301504);
    ushort_t* Kl    = (ushort_t*)(ws + 29884416);
    ushort_t* Vl    = (ushort_t*)(ws + 42467328);
    ushort_t* attnb = (ushort_t*)(ws + 55050240);

    cast_all<<<dim3(3072, 5), 256, 0, stream>>>(x, Wq, Wk, Wv, Wo,
                                                xb, wqb, wkb, wvb, wob);
    gemm_qkv<<<dim3(6, 64, 3), 256, 0, stream>>>(xb, wqb, wkb, wvb,
                                                 bq, bk, bv, Qh, Kl, Vl);
    flash_bf16<<<dim3(96, 32), 64, 0, stream>>>(Qh, Kl, Vl, attnb);
    gemm_outp<<<dim3(6, 64), 256, 0, stream>>>(attnb, wob, bo, out);
}

// Round 10
// 196.376 us; speedup vs baseline: 1.1321x; 1.0119x over previous
//
#include <hip/hip_runtime.h>
#include <math.h>

// Round 10: z-fused gemm_qkv. One block = 64x128 tile computing Q,K,V:
// A-tile staged ONCE per K-step + 3 W-tiles -> 24 MFMA per wave per
// barrier-pair (was 16 with 2x the A-staging). Grid 6x128 = 768 blocks =
// exactly 3/CU. Per-wave strip epilogues keep Q plain / K,V frag-linear
// (bit-identical to what flash reads). Flash/outp/cast unchanged from R9.

typedef __bf16 bf16x8 __attribute__((ext_vector_type(8)));
typedef float  f32x4  __attribute__((ext_vector_type(4)));
typedef unsigned u32x2 __attribute__((ext_vector_type(2)));
typedef unsigned u32x4 __attribute__((ext_vector_type(4)));
typedef unsigned short ushort_t;

__device__ __forceinline__ unsigned short f2bf(float f) {
    unsigned u = __float_as_uint(f);
    u += 0x7fffu + ((u >> 16) & 1u);          // round-to-nearest-even
    return (unsigned short)(u >> 16);
}
__device__ __forceinline__ unsigned pk16(unsigned short lo, unsigned short hi) {
    return (unsigned)lo | ((unsigned)hi << 16);
}

#define GLL16(g, l)                                                                        \
    __builtin_amdgcn_global_load_lds((const __attribute__((address_space(1))) void*)(g),   \
                                     (__attribute__((address_space(3))) void*)(l), 16, 0, 0)

// ---------------------------------------------------------------------------
// cast fp32 -> bf16: y=0 -> x, y=1..4 -> Wq,Wk,Wv,Wo
// ---------------------------------------------------------------------------
__global__ __launch_bounds__(256)
void cast_all(const float* __restrict__ x,
              const float* __restrict__ w0, const float* __restrict__ w1,
              const float* __restrict__ w2, const float* __restrict__ w3,
              ushort_t* __restrict__ xb, ushort_t* __restrict__ wb0,
              ushort_t* __restrict__ wb1, ushort_t* __restrict__ wb2,
              ushort_t* __restrict__ wb3)
{
    const int y = blockIdx.y;
    const float* s; ushort_t* d; int n;
    switch (y) {
        case 0:  s = x;  d = xb;  n = 8192 * 768; break;
        case 1:  s = w0; d = wb0; n = 768 * 768;  break;
        case 2:  s = w1; d = wb1; n = 768 * 768;  break;
        case 3:  s = w2; d = wb2; n = 768 * 768;  break;
        default: s = w3; d = wb3; n = 768 * 768;  break;
    }
    const int i = (blockIdx.x * 256 + threadIdx.x) * 8;
    if (i >= n) return;
    const float4 f0 = *(const float4*)(s + i);
    const float4 f1 = *(const float4*)(s + i + 4);
    ushort4 p0, p1;
    p0.x = f2bf(f0.x); p0.y = f2bf(f0.y); p0.z = f2bf(f0.z); p0.w = f2bf(f0.w);
    p1.x = f2bf(f1.x); p1.y = f2bf(f1.y); p1.z = f2bf(f1.z); p1.w = f2bf(f1.w);
    *(ushort4*)(d + i)     = p0;
    *(ushort4*)(d + i + 4) = p1;
}

// ---------------------------------------------------------------------------
// Shared GEMM core (used by gemm_outp only now): 128x128, XOR-swizzled LDS.
// ---------------------------------------------------------------------------
__device__ __forceinline__ void gemm_core_mfma(
    const ushort_t* __restrict__ A, const ushort_t* __restrict__ W,
    int m0, int n0, ushort_t* smem, f32x4 acc[4][4])
{
    ushort_t* As = smem;            // 4096 shorts
    ushort_t* Ws = smem + 4096;     // 4096 shorts
    const int tid = threadIdx.x;
    const int L   = tid & 63;
    const int wv  = tid >> 6;
    const int wr  = wv >> 1, wc = wv & 1;
    const int c   = L & 15,  g  = L >> 4;

    const int c0 = tid, c1 = tid + 256;
    const int qs = ((tid & 3) ^ ((tid >> 3) & 3)) * 8;   // swizzled k-chunk
    const ushort_t* a0 = A + (size_t)(m0 + (c0 >> 2)) * 768 + qs;
    const ushort_t* a1 = A + (size_t)(m0 + (c1 >> 2)) * 768 + qs;
    const ushort_t* w0 = W + (size_t)(n0 + (c0 >> 2)) * 768 + qs;
    const ushort_t* w1 = W + (size_t)(n0 + (c1 >> 2)) * 768 + qs;
    const int sg = (g ^ ((c >> 1) & 3)) * 8;             // swizzled read col

#pragma unroll
    for (int i = 0; i < 4; ++i)
#pragma unroll
        for (int j = 0; j < 4; ++j) acc[i][j] = (f32x4){0.f, 0.f, 0.f, 0.f};

    for (int k0 = 0; k0 < 768; k0 += 32) {
        __syncthreads();
        GLL16(a0 + k0, &As[(size_t)c0 * 8]);
        GLL16(a1 + k0, &As[(size_t)c1 * 8]);
        GLL16(w0 + k0, &Ws[(size_t)c0 * 8]);
        GLL16(w1 + k0, &Ws[(size_t)c1 * 8]);
        __syncthreads();
        bf16x8 af[4], bfr[4];
#pragma unroll
        for (int i = 0; i < 4; ++i)
            af[i] = *(const bf16x8*)&As[(wr * 64 + i * 16 + c) * 32 + sg];
#pragma unroll
        for (int j = 0; j < 4; ++j)
            bfr[j] = *(const bf16x8*)&Ws[(wc * 64 + j * 16 + c) * 32 + sg];
#pragma unroll
        for (int i = 0; i < 4; ++i)
#pragma unroll
            for (int j = 0; j < 4; ++j)
                acc[i][j] = __builtin_amdgcn_mfma_f32_16x16x32_bf16(
                    af[i], bfr[j], acc[i][j], 0, 0, 0);
    }
}

// ---------------------------------------------------------------------------
// Z-fused QKV GEMM. Block = 64 m-rows x 128 n-cols, 4 waves (64x32 each).
// Per K-step: stage A once (1 GLL16/thr) + Wq,Wk,Wv (2 each) -> 24 MFMA/wave
// per barrier-pair. Epilogues: per-wave LDS strips -> 16B stores; K and V in
// the frag-linear layouts flash consumes.
// ---------------------------------------------------------------------------
__global__ __launch_bounds__(256, 3)
void gemm_qkv(const ushort_t* __restrict__ xb,
              const ushort_t* __restrict__ wqb, const ushort_t* __restrict__ wkb,
              const ushort_t* __restrict__ wvb,
              const float* __restrict__ bq, const float* __restrict__ bk,
              const float* __restrict__ bv,
              ushort_t* __restrict__ Qh, ushort_t* __restrict__ Kl,
              ushort_t* __restrict__ Vl)
{
    __shared__ ushort_t smem[14336];     // As 2048 | Ws0,Ws1,Ws2 4096 each
    ushort_t* As  = smem;
    ushort_t* Ws0 = smem + 2048;
    ushort_t* Ws1 = smem + 6144;
    ushort_t* Ws2 = smem + 10240;

    const int tid = threadIdx.x, L = tid & 63, wv = tid >> 6;
    const int c = L & 15, g = L >> 4;
    const int n0 = blockIdx.x * 128, m0 = blockIdx.y * 64;

    const int qs = ((tid & 3) ^ ((tid >> 3) & 3)) * 8;   // swizzled k-chunk
    const ushort_t* ap = xb  + (size_t)(m0 + (tid >> 2)) * 768 + qs;
    const ushort_t* wq = wqb + (size_t)(n0 + (tid >> 2)) * 768 + qs;
    const ushort_t* wk = wkb + (size_t)(n0 + (tid >> 2)) * 768 + qs;
    const ushort_t* wvp = wvb + (size_t)(n0 + (tid >> 2)) * 768 + qs;
    const size_t st64 = (size_t)64 * 768;
    const int sg = (g ^ ((c >> 1) & 3)) * 8;             // swizzled read col

    f32x4 acc[3][4][2];
#pragma unroll
    for (int z = 0; z < 3; ++z)
#pragma unroll
        for (int i = 0; i < 4; ++i)
#pragma unroll
            for (int j = 0; j < 2; ++j) acc[z][i][j] = (f32x4){0.f, 0.f, 0.f, 0.f};

    for (int k0 = 0; k0 < 768; k0 += 32) {
        __syncthreads();
        GLL16(ap + k0,          &As[(size_t)tid * 8]);
        GLL16(wq + k0,          &Ws0[(size_t)tid * 8]);
        GLL16(wq + st64 + k0,   &Ws0[(size_t)(tid + 256) * 8]);
        GLL16(wk + k0,          &Ws1[(size_t)tid * 8]);
        GLL16(wk + st64 + k0,   &Ws1[(size_t)(tid + 256) * 8]);
        GLL16(wvp + k0,         &Ws2[(size_t)tid * 8]);
        GLL16(wvp + st64 + k0,  &Ws2[(size_t)(tid + 256) * 8]);
        __syncthreads();
        bf16x8 af[4];
#pragma unroll
        for (int i = 0; i < 4; ++i)
            af[i] = *(const bf16x8*)&As[(i * 16 + c) * 32 + sg];
        bf16x8 bf[3][2];
        const ushort_t* wsz[3] = {Ws0, Ws1, Ws2};
#pragma unroll
        for (int z = 0; z < 3; ++z)
#pragma unroll
            for (int j = 0; j < 2; ++j)
                bf[z][j] = *(const bf16x8*)&wsz[z][(wv * 32 + j * 16 + c) * 32 + sg];
#pragma unroll
        for (int z = 0; z < 3; ++z)
#pragma unroll
            for (int i = 0; i < 4; ++i)
#pragma unroll
                for (int j = 0; j < 2; ++j)
                    acc[z][i][j] = __builtin_amdgcn_mfma_f32_16x16x32_bf16(
                        af[i], bf[z][j], acc[z][i][j], 0, 0, 0);
    }

    // ---------------- epilogues (per-wave private strips) ----------------
    const int b  = m0 >> 10, nb = m0 & 1023;
    const int hcol = n0 + wv * 32;
    const int h = hcol >> 6, uh = (hcol >> 5) & 1;
    const int bh = b * 12 + h;
    ushort_t* scr = smem + wv * 2304;

    float bias2[3][2];
#pragma unroll
    for (int j = 0; j < 2; ++j) {
        bias2[0][j] = bq[hcol + j * 16 + c];
        bias2[1][j] = bk[hcol + j * 16 + c];
        bias2[2][j] = bv[hcol + j * 16 + c];
    }

    __syncthreads();   // staging LDS -> scratch

    // z=0: Q plain [bh][token][hd64]; token-major strip [64][36]
#pragma unroll
    for (int i = 0; i < 4; ++i)
#pragma unroll
        for (int j = 0; j < 2; ++j)
#pragma unroll
            for (int r = 0; r < 4; ++r)
                scr[(i * 16 + g * 4 + r) * 36 + j * 16 + c] =
                    f2bf(acc[0][i][j][r] + bias2[0][j]);
#pragma unroll
    for (int e = 0; e < 4; ++e) {
        const int slot = e * 64 + L;
        const int row = slot >> 2, ch = slot & 3;
        const u32x4 v = *(const u32x4*)&scr[row * 36 + ch * 8];
        *(u32x4*)&Qh[((size_t)bh * 1024 + nb + row) * 64 + uh * 32 + ch * 8] = v;
    }

    // z=1: K frag-linear; token-major strip again
#pragma unroll
    for (int i = 0; i < 4; ++i)
#pragma unroll
        for (int j = 0; j < 2; ++j)
#pragma unroll
            for (int r = 0; r < 4; ++r)
                scr[(i * 16 + g * 4 + r) * 36 + j * 16 + c] =
                    f2bf(acc[1][i][j][r] + bias2[1][j]);
#pragma unroll
    for (int tau = 0; tau < 4; ++tau) {
        const u32x4 v = *(const u32x4*)&scr[(tau * 16 + c) * 36 + g * 8];
        *(u32x4*)&Kl[(((size_t)bh * 64 + (nb >> 4) + tau) * 2 + uh) * 512
                     + (size_t)L * 8] = v;
    }

    // z=2: V frag-linear; hd-major strip [32][68]
#pragma unroll
    for (int i = 0; i < 4; ++i)
#pragma unroll
        for (int j = 0; j < 2; ++j)
#pragma unroll
            for (int r = 0; r < 4; ++r)
                scr[(j * 16 + c) * 68 + i * 16 + g * 4 + r] =
                    f2bf(acc[2][i][j][r] + bias2[2][j]);
    const int T = nb >> 6;
#pragma unroll
    for (int t = 0; t < 4; ++t) {
        const int htl = t >> 1, u = t & 1;
        const u32x4 v = *(const u32x4*)&scr[(htl * 16 + c) * 68 + u * 32 + g * 8];
        *(u32x4*)&Vl[((((size_t)bh * 4 + uh * 2 + htl) * 16 + T) * 2 + u) * 512
                     + (size_t)L * 8] = v;
    }
}

__global__ __launch_bounds__(256, 3)
void gemm_outp(const ushort_t* __restrict__ attnb, const ushort_t* __restrict__ wob,
               const float* __restrict__ bo, float* __restrict__ out)
{
    __shared__ ushort_t smem[8192];
    const int m0 = blockIdx.y * 128, n0 = blockIdx.x * 128;
    f32x4 acc[4][4];
    gemm_core_mfma(attnb, wob, m0, n0, smem, acc);
    const int tid = threadIdx.x, L = tid & 63, wv2 = tid >> 6;
    const int wr = wv2 >> 1, wc = wv2 & 1, c = L & 15, g = L >> 4;
#pragma unroll
    for (int i = 0; i < 4; ++i) {
        const int row = m0 + wr * 64 + i * 16 + g * 4;
#pragma unroll
        for (int j = 0; j < 4; ++j) {
            const int col = n0 + wc * 64 + j * 16 + c;
            const float bsvo = bo[col];
#pragma unroll
            for (int r = 0; r < 4; ++r)
                out[(size_t)(row + r) * 768 + col] = acc[i][j][r] + bsvo;
        }
    }
}

// ---------------------------------------------------------------------------
// Flash (R9): S^T = K.Q^T, fixed-max softmax (m=0), 1 wave/block, 32 q-rows.
// Grid (96 bh, 32 qtile) -> q-tiles of one bh share an XCD. All K/V loads
// coalesced 1KB (frag-linear). Bare v_exp_f32 softmax.
// ---------------------------------------------------------------------------
__global__ __launch_bounds__(64, 3)
void flash_bf16(const ushort_t* __restrict__ Q, const ushort_t* __restrict__ Kl,
                const ushort_t* __restrict__ Vl, ushort_t* __restrict__ attnb)
{
    __shared__ ushort_t Ps[2][16 * 68];        // per-q-group strip
    const int L = threadIdx.x;                 // 0..63
    const int c = L & 15, g = L >> 4;
    const int bh = blockIdx.x, q0 = blockIdx.y * 32;
    const float SC2 = 0.05205954985329743f;    // 768^-0.5 * log2(e)

    const ushort_t* Qp = Q + ((size_t)bh * 1024 + q0 + c) * 64 + g * 8;
    bf16x8 qf[2][2];
    qf[0][0] = *(const bf16x8*)Qp;
    qf[0][1] = *(const bf16x8*)(Qp + 32);
    qf[1][0] = *(const bf16x8*)(Qp + 16 * 64);
    qf[1][1] = *(const bf16x8*)(Qp + 16 * 64 + 32);

    const ushort_t* Kb = Kl + (size_t)bh * 65536 + (size_t)L * 8;
    const ushort_t* Vb = Vl + (size_t)bh * 65536 + (size_t)L * 8;

    f32x4 o[2][4];
#pragma unroll
    for (int w = 0; w < 2; ++w)
#pragma unroll
        for (int ht = 0; ht < 4; ++ht) o[w][ht] = (f32x4){0.f, 0.f, 0.f, 0.f};
    float ls[2] = {0.f, 0.f};

    bf16x8 kf0[4], kf1[4];
#pragma unroll
    for (int ct = 0; ct < 4; ++ct) {
        kf0[ct] = *(const bf16x8*)(Kb + (size_t)(ct * 2 + 0) * 512);
        kf1[ct] = *(const bf16x8*)(Kb + (size_t)(ct * 2 + 1) * 512);
    }

    for (int T = 0; T < 16; ++T) {
        bf16x8 vf0[4], vf1[4];
#pragma unroll
        for (int ht = 0; ht < 4; ++ht) {
            const ushort_t* vp = Vb + (size_t)((ht * 16 + T) * 2) * 512;
            vf0[ht] = *(const bf16x8*)vp;
            vf1[ht] = *(const bf16x8*)(vp + 512);
        }
        f32x4 s[2][4];
#pragma unroll
        for (int w = 0; w < 2; ++w)
#pragma unroll
            for (int ct = 0; ct < 4; ++ct) {
                f32x4 zz = (f32x4){0.f, 0.f, 0.f, 0.f};
                zz = __builtin_amdgcn_mfma_f32_16x16x32_bf16(kf0[ct], qf[w][0], zz, 0, 0, 0);
                zz = __builtin_amdgcn_mfma_f32_16x16x32_bf16(kf1[ct], qf[w][1], zz, 0, 0, 0);
                s[w][ct] = zz;
            }
        const int Tn = (T < 15) ? T + 1 : 15;
#pragma unroll
        for (int ct = 0; ct < 4; ++ct) {
            const ushort_t* kp = Kb + (size_t)((Tn * 4 + ct) * 2) * 512;
            kf0[ct] = *(const bf16x8*)kp;
            kf1[ct] = *(const bf16x8*)(kp + 512);
        }
#pragma unroll
        for (int w = 0; w < 2; ++w) {
#pragma unroll
            for (int ct = 0; ct < 4; ++ct) {
                float p[4];
#pragma unroll
                for (int r = 0; r < 4; ++r)
                    p[r] = __builtin_amdgcn_exp2f(s[w][ct][r] * SC2);
                ls[w] += (p[0] + p[1]) + (p[2] + p[3]);
                const unsigned w01 = __builtin_amdgcn_perm(
                    __float_as_uint(p[1]), __float_as_uint(p[0]), 0x07060302u);
                const unsigned w23 = __builtin_amdgcn_perm(
                    __float_as_uint(p[3]), __float_as_uint(p[2]), 0x07060302u);
                *(u32x2*)&Ps[w][c * 68 + ct * 16 + g * 4] = (u32x2){w01, w23};
            }
        }
#pragma unroll
        for (int w = 0; w < 2; ++w) {
            const int pb = c * 68 + g * 8;
            const u32x4 pa  = *(const u32x4*)&Ps[w][pb];
            const u32x4 pbv = *(const u32x4*)&Ps[w][pb + 32];
            const bf16x8 pf0 = __builtin_bit_cast(bf16x8, pa);
            const bf16x8 pf1 = __builtin_bit_cast(bf16x8, pbv);
#pragma unroll
            for (int ht = 0; ht < 4; ++ht) {
                o[w][ht] = __builtin_amdgcn_mfma_f32_16x16x32_bf16(vf0[ht], pf0, o[w][ht], 0, 0, 0);
                o[w][ht] = __builtin_amdgcn_mfma_f32_16x16x32_bf16(vf1[ht], pf1, o[w][ht], 0, 0, 0);
            }
        }
    }

    const int b = bh / 12, h = bh % 12;
#pragma unroll
    for (int w = 0; w < 2; ++w) {
        float l = ls[w];
        l += __shfl_xor(l, 16);
        l += __shfl_xor(l, 32);
        const float inv = 1.f / l;
#pragma unroll
        for (int ht = 0; ht < 4; ++ht) {
            const unsigned w0 = pk16(f2bf(o[w][ht][0] * inv), f2bf(o[w][ht][1] * inv));
            const unsigned w1 = pk16(f2bf(o[w][ht][2] * inv), f2bf(o[w][ht][3] * inv));
            *(u32x2*)&Ps[w][c * 68 + ht * 16 + g * 4] = (u32x2){w0, w1};
        }
#pragma unroll
        for (int e = 0; e < 2; ++e) {
            const int row = e * 8 + (L >> 3);
            const int ch  = L & 7;
            const int si  = row * 68 + ch * 8;
            const u32x2 t0 = *(const u32x2*)&Ps[w][si];
            const u32x2 t1 = *(const u32x2*)&Ps[w][si + 4];
            *(u32x4*)&attnb[((size_t)(b * 1024 + q0 + w * 16 + row)) * 768 + h * 64 + ch * 8]
                = (u32x4){t0.x, t0.y, t1.x, t1.y};
        }
    }
}

extern "C" void kernel_launch(void* const* d_in, const int* in_sizes, int n_in,
                              void* d_out, int out_size, void* d_ws, size_t ws_size,
                              hipStream_t stream)
{
    const float* x  = (const float*)d_in[0];
    const float* Wq = (const float*)d_in[1];
    const float* bq = (const float*)d_in[2];
    const float* Wk = (const float*)d_in[3];
    const float* bk = (const float*)d_in[4];
    const float* Wv = (const float*)d_in[5];
    const float* bv = (const float*)d_in[6];
    const float* Wo = (const float*)d_in[7];
    const float* bo = (const float*)d_in[8];
    float* out = (float*)d_out;

    char* ws = (char*)d_ws;
    ushort_t* xb    = (ushort_t*)(ws);
    ushort_t* wqb   = (ushort_t*)(ws + 12582912);
    ushort_t* wkb   = (ushort_t*)(ws + 12582912 + 1179648);
    ushort_t* wvb   = (ushort_t*)(ws + 12582912 + 2359296);
    ushort_t* wob   = (ushort_t*)(ws + 12582912 + 3538944);
    ushort_t* Qh    = (ushort_t*)(ws + 17301504);
    ushort_t* Kl    = (ushort_t*)(ws + 29884416);
    ushort_t* Vl    = (ushort_t*)(ws + 42467328);
    ushort_t* attnb = (ushort_t*)(ws + 55050240);

    cast_all<<<dim3(3072, 5), 256, 0, stream>>>(x, Wq, Wk, Wv, Wo,
                                                xb, wqb, wkb, wvb, wob);
    gemm_qkv<<<dim3(6, 128), 256, 0, stream>>>(xb, wqb, wkb, wvb,
                                               bq, bk, bv, Qh, Kl, Vl);
    flash_bf16<<<dim3(96, 32), 64, 0, stream>>>(Qh, Kl, Vl, attnb);
    gemm_outp<<<dim3(6, 64), 256, 0, stream>>>(attnb, wob, bo, out);
}